// Round 1
// baseline (1258.415 us; speedup 1.0000x reference)
//
#include <hip/hip_runtime.h>

// Problem constants (match reference)
#define N_    100000
#define C_    16
#define F_    16
#define W_    8
#define D_    3
#define NSEG_ 8192
#define BR    16            // rows per block in preconv

// seg / post row = W_*F_ = 128 floats
#define SEGROW (W_*F_)
#define SEGBUF ((size_t)NSEG_ * SEGROW)   // floats per dim

// ---------------------------------------------------------------------------
// Kernel 1: gather + 3x3 pre-conv + relu + atomic segment-sum accumulate.
// Block: 256 threads = 16 rows x 16 filters. Each thread computes all 8 w.
// LDS x tile: rows r0-1 .. r0+16 (18 rows), layout [row][c][wp] with wp in
// [0..11]: wp = w+1 (zero pads at wp=0 and wp>=9). c-stride = 12 floats = 48B
// so &xs[row][c][0] is 16B-aligned -> float4 LDS reads.
// ---------------------------------------------------------------------------
__global__ __launch_bounds__(256) void preconv_seg(
    const float* __restrict__ X, const int* __restrict__ inv,
    const int* __restrict__ index, const float* __restrict__ pre_w,
    const float* __restrict__ pre_b, float* __restrict__ seg)
{
    const int i  = blockIdx.y;          // dim 0..2
    const int r0 = blockIdx.x * BR;     // first output row of this block
    const int t  = threadIdx.x;

    __shared__ __align__(16) float xs[BR + 2][C_][12];
    __shared__ float ws[3][3][C_][F_];  // [kh][kw][cin][cout]
    __shared__ float bs[F_];

    // zero the x tile (covers w-pads and out-of-range halo rows)
    for (int k = t; k < (BR + 2) * C_ * 12; k += 256)
        (&xs[0][0][0])[k] = 0.f;
    // stage weights + bias
    for (int k = t; k < 3 * 3 * C_ * F_; k += 256)
        (&ws[0][0][0][0])[k] = pre_w[i * (3 * 3 * C_ * F_) + k];
    if (t < F_) bs[t] = pre_b[i * F_ + t];
    __syncthreads();

    // gathered load: rows r0-1 .. r0+BR, w = 0..7, c = 0..15
    for (int k = t; k < (BR + 2) * W_ * C_; k += 256) {
        const int row  = k >> 7;        // /128
        const int rest = k & 127;
        const int w    = rest >> 4;
        const int c    = rest & 15;
        const int n    = r0 - 1 + row;
        if (n >= 0 && n < N_) {
            const int src = inv[((size_t)i * N_ + n) * W_ + w];
            xs[row][c][w + 1] = X[(size_t)src * C_ + c];
        }
    }
    __syncthreads();

    const int f   = t & 15;             // output filter
    const int row = t >> 4;             // 0..15 within block
    const int n   = r0 + row;

    float acc[W_];
#pragma unroll
    for (int w = 0; w < W_; ++w) acc[w] = bs[f];

#pragma unroll
    for (int dr = 0; dr < 3; ++dr) {
#pragma unroll
        for (int c = 0; c < C_; ++c) {
            const float* xp = &xs[row + dr][c][0];
            const float4 A  = *(const float4*)(xp);
            const float4 B  = *(const float4*)(xp + 4);
            const float2 Cv = *(const float2*)(xp + 8);
            const float xv[10] = {A.x, A.y, A.z, A.w,
                                  B.x, B.y, B.z, B.w,
                                  Cv.x, Cv.y};
            const float w0 = ws[dr][0][c][f];
            const float w1 = ws[dr][1][c][f];
            const float w2 = ws[dr][2][c][f];
#pragma unroll
            for (int w = 0; w < W_; ++w)
                acc[w] += xv[w] * w0 + xv[w + 1] * w1 + xv[w + 2] * w2;
        }
    }

    if (n < N_) {
        const int s = index[(size_t)i * N_ + n];
        float* base = seg + ((size_t)i * NSEG_ + s) * SEGROW;
#pragma unroll
        for (int w = 0; w < W_; ++w)
            atomicAdd(base + w * F_ + f, fmaxf(acc[w], 0.f));
    }
}

// ---------------------------------------------------------------------------
// Kernel 2: (3,1) post-conv + relu over seg -> post.  One thread per output.
// ---------------------------------------------------------------------------
__global__ __launch_bounds__(256) void postconv(
    const float* __restrict__ seg, const float* __restrict__ post_w,
    const float* __restrict__ post_b, float* __restrict__ post)
{
    const int i = blockIdx.y;
    const int t = threadIdx.x;

    __shared__ float ws[3][F_][F_];     // [kh][fi][fo]
    __shared__ float bs[F_];
    for (int k = t; k < 3 * F_ * F_; k += 256)
        (&ws[0][0][0])[k] = post_w[i * 3 * F_ * F_ + k];
    if (t < F_) bs[t] = post_b[i * F_ + t];
    __syncthreads();

    const int idx = blockIdx.x * 256 + t;   // over NSEG_*W_*F_ = 1,048,576
    const int fo  = idx & 15;
    const int w   = (idx >> 4) & 7;
    const int s   = idx >> 7;

    float acc = bs[fo];
#pragma unroll
    for (int dh = 0; dh < 3; ++dh) {
        const int ss = s + dh - 1;
        if (ss < 0 || ss >= NSEG_) continue;
        const float* sp = seg + ((size_t)i * NSEG_ + ss) * SEGROW + w * F_;
        const float4 s0 = *(const float4*)(sp);
        const float4 s1 = *(const float4*)(sp + 4);
        const float4 s2 = *(const float4*)(sp + 8);
        const float4 s3 = *(const float4*)(sp + 12);
        const float sv[16] = {s0.x, s0.y, s0.z, s0.w, s1.x, s1.y, s1.z, s1.w,
                              s2.x, s2.y, s2.z, s2.w, s3.x, s3.y, s3.z, s3.w};
#pragma unroll
        for (int fi = 0; fi < F_; ++fi)
            acc += sv[fi] * ws[dh][fi][fo];
    }
    post[(size_t)i * SEGBUF + idx] = fmaxf(acc, 0.f);
}

// ---------------------------------------------------------------------------
// Kernel 3: Y[n] = sum_i post[i][index[i][n]]   (float4-vectorized)
// ---------------------------------------------------------------------------
__global__ __launch_bounds__(256) void gather_sum(
    const float* __restrict__ post, const int* __restrict__ index,
    float* __restrict__ Y)
{
    const int gt = blockIdx.x * 256 + threadIdx.x;  // over N_*32 float4
    if (gt >= N_ * 32) return;
    const int q = gt & 31;          // which float4 within the 128-float row
    const int n = gt >> 5;

    float4 acc = make_float4(0.f, 0.f, 0.f, 0.f);
#pragma unroll
    for (int i = 0; i < D_; ++i) {
        const int s = index[(size_t)i * N_ + n];
        const float4 v = *(const float4*)&post[(size_t)i * SEGBUF +
                                               (size_t)s * SEGROW + q * 4];
        acc.x += v.x; acc.y += v.y; acc.z += v.z; acc.w += v.w;
    }
    *(float4*)&Y[(size_t)n * SEGROW + q * 4] = acc;
}

// ---------------------------------------------------------------------------
extern "C" void kernel_launch(void* const* d_in, const int* in_sizes, int n_in,
                              void* d_out, int out_size, void* d_ws, size_t ws_size,
                              hipStream_t stream)
{
    const float* X      = (const float*)d_in[0];
    const int*   inv    = (const int*)  d_in[1];
    const int*   index  = (const int*)  d_in[2];
    const float* pre_w  = (const float*)d_in[3];
    const float* pre_b  = (const float*)d_in[4];
    const float* post_w = (const float*)d_in[5];
    const float* post_b = (const float*)d_in[6];
    float*       Y      = (float*)d_out;

    // workspace: seg[3][NSEG][128] then post[3][NSEG][128]  (~25.2 MB total)
    float* seg  = (float*)d_ws;
    float* post = seg + D_ * SEGBUF;

    hipMemsetAsync(seg, 0, D_ * SEGBUF * sizeof(float), stream);

    preconv_seg<<<dim3(N_ / BR, D_), 256, 0, stream>>>(X, inv, index,
                                                       pre_w, pre_b, seg);
    postconv<<<dim3((NSEG_ * W_ * F_) / 256, D_), 256, 0, stream>>>(
        seg, post_w, post_b, post);
    gather_sum<<<dim3((N_ * 32 + 255) / 256), 256, 0, stream>>>(post, index, Y);
}

// Round 2
// 291.529 us; speedup vs baseline: 4.3166x; 4.3166x over previous
//
#include <hip/hip_runtime.h>

// Problem constants (match reference)
#define N_    100000
#define C_    16
#define F_    16
#define W_    8
#define D_    3
#define NSEG_ 8192
#define BR    16            // n-rows per block in preconv

#define SEGROW (W_*F_)                       // 128 floats
#define SEGBUF ((size_t)NSEG_ * SEGROW)      // floats per dim

typedef __attribute__((ext_vector_type(4))) float f32x4;
typedef __attribute__((ext_vector_type(8))) short bf16x8;

// float -> bf16 round-to-nearest-even
static __device__ __forceinline__ short f2bf(float x) {
    union { float f; unsigned u; } v; v.f = x;
    unsigned r = v.u + 0x7fffu + ((v.u >> 16) & 1u);
    return (short)(r >> 16);
}

// ---------------------------------------------------------------------------
// Kernel 1: gather + 3x3 pre-conv (im2col GEMM on MFMA) + relu + atomic
// segment accumulate.
//
// Block = 256 thr = 4 waves, covers BR=16 point-rows -> M = 16*8 = 128
// (n,w) output rows. Each wave computes 2 tiles of 16 rows x 16 filters.
// K = 3(dr) * 3(dw) * 16(c) = 144, zero-padded to 160 = 5 x K32 MFMA.
// k -> (dr, dw, c):  k = dr*48 + dw*16 + c.
//
// LDS xg[20][10][16] bf16: gathered X rows r0-1..r0+16 (idx 0..17) with
// w' = w+1 (zero pads w'=0,9); rows 18..19 are the K-pad (dr==3) zeros.
// LDS wbT[16][160] bf16: B^T so B-fragment reads are 16B-contiguous.
// ---------------------------------------------------------------------------
__global__ __launch_bounds__(256) void preconv_seg_mfma(
    const float* __restrict__ X, const int* __restrict__ inv,
    const int* __restrict__ index, const float* __restrict__ pre_w,
    const float* __restrict__ pre_b, float* __restrict__ seg)
{
    const int i  = blockIdx.y;          // dim 0..2
    const int r0 = blockIdx.x * BR;
    const int t  = threadIdx.x;

    __shared__ __align__(16) short xg[20][10][16];   // 6400 B
    __shared__ __align__(16) short wbT[16][160];     // 5120 B
    __shared__ float bs[F_];
    __shared__ int   sidx[BR];

    // zero the x tile (covers w-pads, halo OOB, and K-pad rows 18/19)
    int* xz = (int*)&xg[0][0][0];
    for (int k = t; k < 20 * 10 * 16 / 2; k += 256) xz[k] = 0;

    // weights: wbT[f][k] = bf16(pre_w[i][k][f]), zero for k >= 144
    for (int k = t; k < 16 * 160; k += 256) {
        const int f = k / 160, kk = k - f * 160;
        wbT[f][kk] = (kk < 144) ? f2bf(pre_w[i * 2304 + kk * 16 + f])
                                : (short)0;
    }
    if (t < F_) bs[t] = pre_b[i * F_ + t];
    if (t < BR) sidx[t] = index[(size_t)i * N_ + r0 + t];
    __syncthreads();

    // gather: 144 (row,w) pairs x 2 c-halves; each task = 32B of X -> bf16x8
    for (int k = t; k < 288; k += 256) {
        const int pair = k >> 1, half = k & 1;
        const int row = pair >> 3, w = pair & 7;    // row 0..17
        const int n = r0 - 1 + row;
        if (n >= 0 && n < N_) {
            const int src = inv[((size_t)i * N_ + n) * W_ + w];
            const float4 v0 = *(const float4*)&X[(size_t)src * C_ + half * 8];
            const float4 v1 = *(const float4*)&X[(size_t)src * C_ + half * 8 + 4];
            bf16x8 o;
            o[0] = f2bf(v0.x); o[1] = f2bf(v0.y); o[2] = f2bf(v0.z); o[3] = f2bf(v0.w);
            o[4] = f2bf(v1.x); o[5] = f2bf(v1.y); o[6] = f2bf(v1.z); o[7] = f2bf(v1.w);
            *(bf16x8*)&xg[row][w + 1][half * 8] = o;
        }
    }
    __syncthreads();

    const int lane = t & 63;
    const int wv   = t >> 6;
    const int fc   = lane & 15;     // filter col (A-row index reuses &15)
    const int kb   = lane >> 4;     // k-block 0..3
    const int mA   = lane & 15;     // A-fragment row within tile
    const int rowC0 = kb * 4;       // C/D row base: (lane>>4)*4

#pragma unroll
    for (int tt = 0; tt < 2; ++tt) {
        const int m_base = (wv * 2 + tt) * 16;
        const int m  = m_base + mA;
        const int nl = m >> 3;          // local n (0..15)
        const int w  = m & 7;
        f32x4 acc = {0.f, 0.f, 0.f, 0.f};
#pragma unroll
        for (int s = 0; s < 5; ++s) {
            const int g  = s * 4 + kb;      // 8-wide k-group index
            const int gg = g >> 1;          // (dr,dw) group 0..9
            const int c0 = (g & 1) * 8;
            const int dr = gg / 3;          // 3 -> K-pad (zero rows)
            const int dw = gg - dr * 3;
            const bf16x8 a = *(const bf16x8*)&xg[nl + dr][w + dw][c0];
            const bf16x8 b = *(const bf16x8*)&wbT[fc][s * 32 + kb * 8];
            acc = __builtin_amdgcn_mfma_f32_16x16x32_bf16(a, b, acc, 0, 0, 0);
        }
        // epilogue: C row = (lane>>4)*4 + r, col = lane&15
#pragma unroll
        for (int r = 0; r < 4; ++r) {
            const int mc  = m_base + rowC0 + r;
            const int nlc = mc >> 3, wc = mc & 7;
            const float v = fmaxf(acc[r] + bs[fc], 0.f);
            atomicAdd(&seg[((size_t)i * NSEG_ + sidx[nlc]) * SEGROW + wc * F_ + fc], v);
        }
    }
}

// ---------------------------------------------------------------------------
// Kernel 2: (3,1) post-conv + relu over seg -> post.  One thread per output.
// ---------------------------------------------------------------------------
__global__ __launch_bounds__(256) void postconv(
    const float* __restrict__ seg, const float* __restrict__ post_w,
    const float* __restrict__ post_b, float* __restrict__ post)
{
    const int i = blockIdx.y;
    const int t = threadIdx.x;

    __shared__ float ws[3][F_][F_];     // [kh][fi][fo]
    __shared__ float bs[F_];
    for (int k = t; k < 3 * F_ * F_; k += 256)
        (&ws[0][0][0])[k] = post_w[i * 3 * F_ * F_ + k];
    if (t < F_) bs[t] = post_b[i * F_ + t];
    __syncthreads();

    const int idx = blockIdx.x * 256 + t;   // over NSEG_*W_*F_ = 1,048,576
    const int fo  = idx & 15;
    const int w   = (idx >> 4) & 7;
    const int s   = idx >> 7;

    float acc = bs[fo];
#pragma unroll
    for (int dh = 0; dh < 3; ++dh) {
        const int ss = s + dh - 1;
        if (ss < 0 || ss >= NSEG_) continue;
        const float* sp = seg + ((size_t)i * NSEG_ + ss) * SEGROW + w * F_;
        const float4 s0 = *(const float4*)(sp);
        const float4 s1 = *(const float4*)(sp + 4);
        const float4 s2 = *(const float4*)(sp + 8);
        const float4 s3 = *(const float4*)(sp + 12);
        const float sv[16] = {s0.x, s0.y, s0.z, s0.w, s1.x, s1.y, s1.z, s1.w,
                              s2.x, s2.y, s2.z, s2.w, s3.x, s3.y, s3.z, s3.w};
#pragma unroll
        for (int fi = 0; fi < F_; ++fi)
            acc += sv[fi] * ws[dh][fi][fo];
    }
    post[(size_t)i * SEGBUF + idx] = fmaxf(acc, 0.f);
}

// ---------------------------------------------------------------------------
// Kernel 3: Y[n] = sum_i post[i][index[i][n]]   (float4-vectorized)
// ---------------------------------------------------------------------------
__global__ __launch_bounds__(256) void gather_sum(
    const float* __restrict__ post, const int* __restrict__ index,
    float* __restrict__ Y)
{
    const int gt = blockIdx.x * 256 + threadIdx.x;  // over N_*32 float4
    if (gt >= N_ * 32) return;
    const int q = gt & 31;
    const int n = gt >> 5;

    float4 acc = make_float4(0.f, 0.f, 0.f, 0.f);
#pragma unroll
    for (int i = 0; i < D_; ++i) {
        const int s = index[(size_t)i * N_ + n];
        const float4 v = *(const float4*)&post[(size_t)i * SEGBUF +
                                               (size_t)s * SEGROW + q * 4];
        acc.x += v.x; acc.y += v.y; acc.z += v.z; acc.w += v.w;
    }
    *(float4*)&Y[(size_t)n * SEGROW + q * 4] = acc;
}

// ---------------------------------------------------------------------------
extern "C" void kernel_launch(void* const* d_in, const int* in_sizes, int n_in,
                              void* d_out, int out_size, void* d_ws, size_t ws_size,
                              hipStream_t stream)
{
    const float* X      = (const float*)d_in[0];
    const int*   inv    = (const int*)  d_in[1];
    const int*   index  = (const int*)  d_in[2];
    const float* pre_w  = (const float*)d_in[3];
    const float* pre_b  = (const float*)d_in[4];
    const float* post_w = (const float*)d_in[5];
    const float* post_b = (const float*)d_in[6];
    float*       Y      = (float*)d_out;

    float* seg  = (float*)d_ws;                 // [3][NSEG][128]
    float* post = seg + D_ * SEGBUF;            // [3][NSEG][128]

    hipMemsetAsync(seg, 0, D_ * SEGBUF * sizeof(float), stream);

    preconv_seg_mfma<<<dim3(N_ / BR, D_), 256, 0, stream>>>(
        X, inv, index, pre_w, pre_b, seg);
    postconv<<<dim3((NSEG_ * W_ * F_) / 256, D_), 256, 0, stream>>>(
        seg, post_w, post_b, post);
    gather_sum<<<dim3((N_ * 32 + 255) / 256), 256, 0, stream>>>(post, index, Y);
}